// Round 7
// baseline (145.854 us; speedup 1.0000x reference)
//
#include <hip/hip_runtime.h>

// NTXentLoss, B=8192, D=128, T=0.1, idx=0. fp32 in, fp32 scalar out.
// R6 post-mortem: LDS ping-pong can't pipeline -- __syncthreads drains
// vmcnt(0), killing the prefetch (m97 barrier-drain). Key insight: bf16
// row-major [row][k] IS the MFMA fragment layout, and Zib+Zjb total 4 MB
// (L2-resident) -> skip LDS entirely, stream fragments global->VGPR with
// zero barriers in the K-loop. Memsets folded into prep (3 dispatches).

#define BB 8192
#define DD 128
#define TM 128
#define TN 128

typedef __attribute__((ext_vector_type(8))) short short8;
typedef __attribute__((ext_vector_type(4))) float floatx4;

static __device__ __forceinline__ float wave_sum(float v) {
#pragma unroll
    for (int off = 32; off > 0; off >>= 1) v += __shfl_xor(v, off, 64);
    return v;
}

static __device__ __forceinline__ unsigned short f2bf(float f) {
    unsigned int u = __float_as_uint(f);
    return (unsigned short)((u + 0x7FFFu + ((u >> 16) & 1u)) >> 16);
}

// ---- prep: normalize rows -> bf16 copies + 1/norm; zero denom and out ----
__global__ __launch_bounds__(256) void prep_kernel(
    const float* __restrict__ zis, const float* __restrict__ zjs,
    unsigned short* __restrict__ Zib, unsigned short* __restrict__ Zjb,
    float* __restrict__ rni, float* __restrict__ rnj,
    float* __restrict__ denom, float* __restrict__ out)
{
    int tid = threadIdx.x;
    if (blockIdx.x < 32) denom[blockIdx.x * 256 + tid] = 0.0f;   // 32*256 = BB
    if (blockIdx.x == 0 && tid == 0) out[0] = 0.0f;

    int wave = tid >> 6, lane = tid & 63;
    int row = blockIdx.x * 4 + wave;
    const float* src; unsigned short* dst; float* rn; int r;
    if (row < BB) { src = zis; dst = Zib; rn = rni; r = row; }
    else          { src = zjs; dst = Zjb; rn = rnj; r = row - BB; }
    float2 u = *(const float2*)(src + (size_t)r * DD + lane * 2);
    float s = wave_sum(u.x * u.x + u.y * u.y);
    float sc = 1.0f / sqrtf(s);
    if (lane == 0) rn[r] = sc;
    ushort2 o; o.x = f2bf(u.x * sc); o.y = f2bf(u.y * sc);
    *(ushort2*)(dst + (size_t)r * DD + lane * 2) = o;
}

// ---- 128x128 MFMA tile, LDS-free fragment streaming ----------------------
// Row-major bf16 [row][128] == MFMA operand layout: lane(quad,l15) of
// fragment (t,kc) reads 16 B at row (base + t*16 + l15), k = kc*32+quad*8.
// All fragment loads hit L2 (4 MB working set); no barriers in K-loop.
__global__ __launch_bounds__(256) void mfma_tile_kernel(
    const unsigned short* __restrict__ Zjb,   // A: zj normalized
    const unsigned short* __restrict__ Zib,   // B: zi normalized
    const int* __restrict__ ilab, const int* __restrict__ jlab,
    float* __restrict__ denom)
{
    __shared__ int   il[TN];
    __shared__ int   jl[TM];
    __shared__ float rowsum[TM];

    int tid  = threadIdx.x;
    int lane = tid & 63, wave = tid >> 6;
    int wm = wave >> 1, wn = wave & 1;        // 2x2 wave grid, 64x64 each
    int quad = lane >> 4, l15 = lane & 15;
    int i0 = blockIdx.y * TM, j0 = blockIdx.x * TN;

    if (tid < TN) { il[tid] = ilab[j0 + tid]; rowsum[tid] = 0.0f; }
    else          { jl[tid - 128] = jlab[i0 + tid - 128]; }
    __syncthreads();                          // labels/rowsum ready (only barrier)

    floatx4 acc[4][4];
#pragma unroll
    for (int a = 0; a < 4; ++a)
#pragma unroll
        for (int b = 0; b < 4; ++b) acc[a][b] = (floatx4){0.f, 0.f, 0.f, 0.f};

    // per-fragment-row base pointers (lane-resolved): row*DD + quad*8
    const unsigned short* abase[4];
    const unsigned short* bbase[4];
#pragma unroll
    for (int t = 0; t < 4; ++t) {
        abase[t] = Zjb + (size_t)(i0 + wm * 64 + t * 16 + l15) * DD + quad * 8;
        bbase[t] = Zib + (size_t)(j0 + wn * 64 + t * 16 + l15) * DD + quad * 8;
    }

#pragma unroll
    for (int kc = 0; kc < 4; ++kc) {          // K = 4 chunks x 32
        short8 af[4], bfr[4];
#pragma unroll
        for (int t = 0; t < 4; ++t) {
            af[t]  = *(const short8*)(abase[t] + kc * 32);
            bfr[t] = *(const short8*)(bbase[t] + kc * 32);
        }
#pragma unroll
        for (int mt = 0; mt < 4; ++mt)
#pragma unroll
            for (int nt = 0; nt < 4; ++nt)
                acc[mt][nt] = __builtin_amdgcn_mfma_f32_16x16x32_bf16(
                    af[mt], bfr[nt], acc[mt][nt], 0, 0, 0);
    }

    // epilogue: e = exp(10*c-10), mask, row-sum (C/D: col=l15, row=quad*4+r)
#pragma unroll
    for (int mt = 0; mt < 4; ++mt) {
#pragma unroll
        for (int r = 0; r < 4; ++r) {
            int rowl = wm * 64 + mt * 16 + quad * 4 + r;
            int jr = jl[rowl];
            float s = 0.0f;
#pragma unroll
            for (int nt = 0; nt < 4; ++nt) {
                int col = wn * 64 + nt * 16 + l15;
                float e = __expf(fmaf(acc[mt][nt][r], 10.0f, -10.0f));
                s += (il[col] != jr) ? e : 0.0f;
            }
            s += __shfl_xor(s, 1, 64);
            s += __shfl_xor(s, 2, 64);
            s += __shfl_xor(s, 4, 64);
            s += __shfl_xor(s, 8, 64);
            if (l15 == 0) atomicAdd(&rowsum[rowl], s);
        }
    }
    __syncthreads();
    if (tid < TM) atomicAdd(&denom[i0 + tid], rowsum[tid]);
}

// ---- fused pos + finalize (512 blocks, 1 atomic/block) -------------------
__global__ __launch_bounds__(256) void posfinal_kernel(
    const float* __restrict__ zis, const float* __restrict__ zjs,
    const float* __restrict__ rni, const float* __restrict__ rnj,
    const float* __restrict__ denom, const float* __restrict__ wts,
    const int* __restrict__ idxp, float* __restrict__ out)
{
    int wave = threadIdx.x >> 6, lane = threadIdx.x & 63;
    int idx = idxp[0];
    float ll = 0.0f;
#pragma unroll
    for (int t = 0; t < 4; ++t) {
        int i = blockIdx.x * 16 + wave * 4 + t;
        int j = idx + i;
        float2 a  = *(const float2*)(zjs + (size_t)i * DD + lane * 2);
        float2 b2 = *(const float2*)(zis + (size_t)j * DD + lane * 2);
        float s = wave_sum(a.x * b2.x + a.y * b2.y);
        if (lane == 0) {
            float p = s * rni[j] * rnj[i] * 10.0f;
            float l = 10.0f + logf(__expf(p - 10.0f) + denom[i]) - p;
            float w = wts[j];
            ll += (l * w) / w;    // faithful to reference's weighted mean
        }
    }
    __shared__ float part[4];
    if (lane == 0) part[wave] = ll;
    __syncthreads();
    if (threadIdx.x == 0)
        atomicAdd(out, (part[0] + part[1] + part[2] + part[3]) * (1.0f / BB));
}

// ---- launch --------------------------------------------------------------
extern "C" void kernel_launch(void* const* d_in, const int* in_sizes, int n_in,
                              void* d_out, int out_size, void* d_ws, size_t ws_size,
                              hipStream_t stream) {
    const float* zis = (const float*)d_in[0];
    const float* zjs = (const float*)d_in[1];
    const int* ilab = (const int*)d_in[2];
    const int* jlab = (const int*)d_in[3];
    const float* wts = (const float*)d_in[4];
    const int* idxp = (const int*)d_in[5];
    float* out = (float*)d_out;

    float* rni   = (float*)d_ws;
    float* rnj   = rni + BB;
    float* denom = rnj + BB;
    unsigned short* Zib = (unsigned short*)(denom + BB);  // [BB][DD] bf16
    unsigned short* Zjb = Zib + (size_t)BB * DD;

    prep_kernel<<<2 * BB / 4, 256, 0, stream>>>(
        zis, zjs, Zib, Zjb, rni, rnj, denom, out);
    mfma_tile_kernel<<<dim3(BB / TN, BB / TM), 256, 0, stream>>>(
        Zjb, Zib, ilab, jlab, denom);
    posfinal_kernel<<<BB / 16, 256, 0, stream>>>(
        zis, zjs, rni, rnj, denom, wts, idxp, out);
}